// Round 2
// baseline (4898.633 us; speedup 1.0000x reference)
//
#include <hip/hip_runtime.h>

#define NN 50000
#define NE 800000
#define C 64
#define NL 4
#define NPB 32            // nodes per fused block
#define SCAN_NB 196       // ceil(50000/256)

// ---------------- degree histogram (int) ----------------
__global__ void hist_kernel(const int* __restrict__ dst, int* __restrict__ deg_cnt) {
    int i = blockIdx.x * blockDim.x + threadIdx.x;
    int stride = gridDim.x * blockDim.x;
    for (int e = i; e < NE; e += stride)
        atomicAdd(&deg_cnt[dst[e]], 1);
}

__global__ void deginv_kernel(const int* __restrict__ deg_cnt, float* __restrict__ deg_inv) {
    int i = blockIdx.x * blockDim.x + threadIdx.x;
    if (i < NN) deg_inv[i] = 1.0f / fmaxf((float)deg_cnt[i], 1.0f);
}

// ---------------- 3-kernel exclusive scan over deg_cnt -> row_start ----------------
__global__ __launch_bounds__(256) void scan1_kernel(const int* __restrict__ deg_cnt,
                                                    int* __restrict__ row_start,
                                                    int* __restrict__ bsums) {
    __shared__ int sdata[256];
    int tid = threadIdx.x;
    int i = blockIdx.x * 256 + tid;
    int v = (i < NN) ? deg_cnt[i] : 0;
    sdata[tid] = v;
    __syncthreads();
    for (int off = 1; off < 256; off <<= 1) {
        int t = (tid >= off) ? sdata[tid - off] : 0;
        __syncthreads();
        sdata[tid] += t;
        __syncthreads();
    }
    int incl = sdata[tid];
    if (i < NN) row_start[i] = incl - v;       // exclusive within block
    if (tid == 255) bsums[blockIdx.x] = incl;  // block total
}

__global__ __launch_bounds__(256) void scan2_kernel(int* __restrict__ bsums) {
    __shared__ int sdata[256];
    int tid = threadIdx.x;
    int v = (tid < SCAN_NB) ? bsums[tid] : 0;
    sdata[tid] = v;
    __syncthreads();
    for (int off = 1; off < 256; off <<= 1) {
        int t = (tid >= off) ? sdata[tid - off] : 0;
        __syncthreads();
        sdata[tid] += t;
        __syncthreads();
    }
    if (tid < SCAN_NB) bsums[tid] = sdata[tid] - v;  // exclusive
}

__global__ void scan3_kernel(int* __restrict__ row_start, const int* __restrict__ bsums,
                             int* __restrict__ cursor) {
    int i = blockIdx.x * blockDim.x + threadIdx.x;
    if (i < NN) {
        int rs = row_start[i] + bsums[i >> 8];
        row_start[i] = rs;
        cursor[i] = rs;
    }
}

// ---------------- CSR fill ----------------
__global__ void fill_kernel(const int* __restrict__ src, const int* __restrict__ dst,
                            int* __restrict__ cursor, int* __restrict__ csr_src) {
    int i = blockIdx.x * blockDim.x + threadIdx.x;
    int stride = gridDim.x * blockDim.x;
    for (int e = i; e < NE; e += stride) {
        int slot = atomicAdd(&cursor[dst[e]], 1);
        csr_src[slot] = src[e];
    }
}

// ---------------- fused layer: gather-mean + (agg@Wl + x@Wr + b) + PReLU ----------------
__global__ __launch_bounds__(512) void fused_layer(
    const float* __restrict__ xin, const int* __restrict__ deg_cnt,
    const int* __restrict__ row_start, const int* __restrict__ csr_src,
    const float* __restrict__ deg_inv,
    const float* __restrict__ Wl, const float* __restrict__ Wr,
    const float* __restrict__ bias, const float* __restrict__ alpha,
    float* __restrict__ xout)
{
    __shared__ float wl[C * C];           // [k][c], 16KB
    __shared__ float wr[C * C];           // 16KB
    __shared__ float as_[NPB][C + 1];     // padded to kill bank conflicts
    __shared__ float xs[NPB][C + 1];
    __shared__ float bs[C];
    __shared__ float als[C];

    int tid = threadIdx.x;
    for (int i = tid; i < C * C; i += 512) {
        wl[i] = Wl[i];
        wr[i] = Wr[i];
    }
    if (tid < C) {
        bs[tid] = bias[tid];
        als[tid] = alpha[tid];
    }

    int node0 = blockIdx.x * NPB;
    int w = tid >> 6;        // wave 0..7
    int lane = tid & 63;

    // gather phase: wave w handles nodes w*4 .. w*4+3, lane = channel
    for (int r = 0; r < 4; r++) {
        int nl = w * 4 + r;
        int n = node0 + nl;
        float acc = 0.f, xv = 0.f;
        if (n < NN) {
            int rs = row_start[n];
            int cnt = deg_cnt[n];
            for (int base = 0; base < cnt; base += 64) {
                int m = cnt - base;
                if (m > 64) m = 64;
                int myidx = (lane < m) ? csr_src[rs + base + lane] : 0;
                for (int t = 0; t < m; t++) {
                    int s = __shfl(myidx, t);
                    acc += xin[s * C + lane];
                }
            }
            acc *= deg_inv[n];
            xv = xin[n * C + lane];
        }
        as_[nl][lane] = acc;
        xs[nl][lane] = xv;
    }
    __syncthreads();

    // GEMM phase: lane owns node (w*4 + lane>>4), channels c0..c0+3
    int nl = w * 4 + (lane >> 4);
    int n = node0 + nl;
    int c0 = (lane & 15) * 4;
    float4 acc4 = make_float4(bs[c0], bs[c0 + 1], bs[c0 + 2], bs[c0 + 3]);
    #pragma unroll
    for (int k = 0; k < C; k++) {
        float a = as_[nl][k];
        float xv = xs[nl][k];
        const float4 wlv = *(const float4*)&wl[k * C + c0];
        const float4 wrv = *(const float4*)&wr[k * C + c0];
        acc4.x += a * wlv.x + xv * wrv.x;
        acc4.y += a * wlv.y + xv * wrv.y;
        acc4.z += a * wlv.z + xv * wrv.z;
        acc4.w += a * wlv.w + xv * wrv.w;
    }
    if (n < NN) {
        float4 o;
        o.x = acc4.x >= 0.f ? acc4.x : als[c0] * acc4.x;
        o.y = acc4.y >= 0.f ? acc4.y : als[c0 + 1] * acc4.y;
        o.z = acc4.z >= 0.f ? acc4.z : als[c0 + 2] * acc4.z;
        o.w = acc4.w >= 0.f ? acc4.w : als[c0 + 3] * acc4.w;
        *(float4*)&xout[n * C + c0] = o;
    }
}

extern "C" void kernel_launch(void* const* d_in, const int* in_sizes, int n_in,
                              void* d_out, int out_size, void* d_ws, size_t ws_size,
                              hipStream_t stream) {
    const float* x     = (const float*)d_in[0];
    const int*   ei    = (const int*)d_in[1];
    const float* Wl    = (const float*)d_in[2];
    const float* Wr    = (const float*)d_in[3];
    const float* b     = (const float*)d_in[4];
    const float* alpha = (const float*)d_in[5];
    float* out = (float*)d_out;

    const int* src = ei;        // edge_index[0]
    const int* dst = ei + NE;   // edge_index[1]

    // workspace layout
    char* wsp = (char*)d_ws;
    float* deg_inv   = (float*)wsp;                 wsp += (size_t)NN * 4;
    int*   deg_cnt   = (int*)wsp;                   wsp += (size_t)NN * 4;
    int*   row_start = (int*)wsp;                   wsp += (size_t)NN * 4;
    int*   cursor    = (int*)wsp;                   wsp += (size_t)NN * 4;
    int*   bsums     = (int*)wsp;                   wsp += 256 * 4;
    int*   csr_src   = (int*)wsp;                   wsp += (size_t)NE * 4;
    float* x0        = (float*)wsp;                 wsp += (size_t)NN * C * 4;
    float* x1        = (float*)wsp;

    // ---- CSR build (per call; deterministic up to within-row order) ----
    hipMemsetAsync(deg_cnt, 0, NN * sizeof(int), stream);
    hist_kernel<<<2048, 256, 0, stream>>>(dst, deg_cnt);
    deginv_kernel<<<(NN + 255) / 256, 256, 0, stream>>>(deg_cnt, deg_inv);
    scan1_kernel<<<SCAN_NB, 256, 0, stream>>>(deg_cnt, row_start, bsums);
    scan2_kernel<<<1, 256, 0, stream>>>(bsums);
    scan3_kernel<<<(NN + 255) / 256, 256, 0, stream>>>(row_start, bsums, cursor);
    fill_kernel<<<2048, 256, 0, stream>>>(src, dst, cursor, csr_src);

    // ---- 4 fused layers ----
    const int nblocks = (NN + NPB - 1) / NPB;
    const float* cur = x;
    for (int l = 0; l < NL; l++) {
        float* dest = (l == NL - 1) ? out : ((l & 1) ? x1 : x0);
        fused_layer<<<nblocks, 512, 0, stream>>>(cur, deg_cnt, row_start, csr_src, deg_inv,
                                                 Wl + (size_t)l * C * C,
                                                 Wr + (size_t)l * C * C,
                                                 b + (size_t)l * C,
                                                 alpha + (size_t)l * C,
                                                 dest);
        cur = dest;
    }
}

// Round 3
// 355.524 us; speedup vs baseline: 13.7786x; 13.7786x over previous
//
#include <hip/hip_runtime.h>

#define NN 50000
#define NE 800000
#define C 64
#define NL 4
#define WPB 8             // waves (=nodes) per fused block
#define SCAN_NB 196       // ceil(50000/256)

// ---------------- degree histogram (int) ----------------
__global__ void hist_kernel(const int* __restrict__ dst, int* __restrict__ deg_cnt) {
    int i = blockIdx.x * blockDim.x + threadIdx.x;
    int stride = gridDim.x * blockDim.x;
    for (int e = i; e < NE; e += stride)
        atomicAdd(&deg_cnt[dst[e]], 1);
}

// ---------------- 3-kernel exclusive scan over deg_cnt -> row_start ----------------
__global__ __launch_bounds__(256) void scan1_kernel(const int* __restrict__ deg_cnt,
                                                    int* __restrict__ row_start,
                                                    int* __restrict__ bsums) {
    __shared__ int sdata[256];
    int tid = threadIdx.x;
    int i = blockIdx.x * 256 + tid;
    int v = (i < NN) ? deg_cnt[i] : 0;
    sdata[tid] = v;
    __syncthreads();
    for (int off = 1; off < 256; off <<= 1) {
        int t = (tid >= off) ? sdata[tid - off] : 0;
        __syncthreads();
        sdata[tid] += t;
        __syncthreads();
    }
    int incl = sdata[tid];
    if (i < NN) row_start[i] = incl - v;
    if (tid == 255) bsums[blockIdx.x] = incl;
}

__global__ __launch_bounds__(256) void scan2_kernel(int* __restrict__ bsums) {
    __shared__ int sdata[256];
    int tid = threadIdx.x;
    int v = (tid < SCAN_NB) ? bsums[tid] : 0;
    sdata[tid] = v;
    __syncthreads();
    for (int off = 1; off < 256; off <<= 1) {
        int t = (tid >= off) ? sdata[tid - off] : 0;
        __syncthreads();
        sdata[tid] += t;
        __syncthreads();
    }
    if (tid < SCAN_NB) bsums[tid] = sdata[tid] - v;
}

__global__ void scan3_kernel(int* __restrict__ row_start, const int* __restrict__ bsums,
                             int* __restrict__ cursor, const int* __restrict__ deg_cnt,
                             float* __restrict__ deg_inv) {
    int i = blockIdx.x * blockDim.x + threadIdx.x;
    if (i < NN) {
        int rs = row_start[i] + bsums[i >> 8];
        row_start[i] = rs;
        cursor[i] = rs;
        deg_inv[i] = 1.0f / fmaxf((float)deg_cnt[i], 1.0f);
    }
}

// ---------------- CSR fill ----------------
__global__ void fill_kernel(const int* __restrict__ src, const int* __restrict__ dst,
                            int* __restrict__ cursor, int* __restrict__ csr_src) {
    int i = blockIdx.x * blockDim.x + threadIdx.x;
    int stride = gridDim.x * blockDim.x;
    for (int e = i; e < NE; e += stride) {
        int slot = atomicAdd(&cursor[dst[e]], 1);
        csr_src[slot] = src[e];
    }
}

// ---------------- fused layer: CSR gather-mean + (agg@Wl + x@Wr + b) + PReLU ----------------
// one wave per node; lane = channel during gather, lane = out-channel during GEMM.
__global__ __launch_bounds__(512) void fused_layer(
    const float* __restrict__ xin, const int* __restrict__ deg_cnt,
    const int* __restrict__ row_start, const int* __restrict__ csr_src,
    const float* __restrict__ deg_inv,
    const float* __restrict__ Wl, const float* __restrict__ Wr,
    const float* __restrict__ bias, const float* __restrict__ alpha,
    float* __restrict__ xout)
{
    __shared__ float wl[C * C];       // [k][c] 16KB
    __shared__ float wr[C * C];       // 16KB
    __shared__ float as_[WPB][C];
    __shared__ float xs[WPB][C];
    __shared__ float bs[C];
    __shared__ float als[C];

    int tid = threadIdx.x;
    // stage weights, vectorized
    const float4* Wl4 = (const float4*)Wl;
    const float4* Wr4 = (const float4*)Wr;
    float4* wl4 = (float4*)wl;
    float4* wr4 = (float4*)wr;
    for (int i = tid; i < C * C / 4; i += 512) {
        wl4[i] = Wl4[i];
        wr4[i] = Wr4[i];
    }
    if (tid < C) {
        bs[tid] = bias[tid];
        als[tid] = alpha[tid];
    }

    int w = tid >> 6;
    int lane = tid & 63;
    int n = blockIdx.x * WPB + w;   // 6250*8 = 50000 exact

    float acc = 0.f, xv = 0.f;
    if (n < NN) {
        int rs = row_start[n];
        int d = deg_cnt[n];
        for (int base = 0; base < d; base += 64) {
            int m = d - base;
            if (m > 64) m = 64;
            int myidx = (lane < m) ? csr_src[rs + base + lane] : 0;
            int t = 0;
            // unroll-by-8: 8 independent 256B row-loads in flight per wave
            for (; t + 8 <= m; t += 8) {
                int s0 = __shfl(myidx, t + 0);
                int s1 = __shfl(myidx, t + 1);
                int s2 = __shfl(myidx, t + 2);
                int s3 = __shfl(myidx, t + 3);
                int s4 = __shfl(myidx, t + 4);
                int s5 = __shfl(myidx, t + 5);
                int s6 = __shfl(myidx, t + 6);
                int s7 = __shfl(myidx, t + 7);
                float v0 = xin[s0 * C + lane];
                float v1 = xin[s1 * C + lane];
                float v2 = xin[s2 * C + lane];
                float v3 = xin[s3 * C + lane];
                float v4 = xin[s4 * C + lane];
                float v5 = xin[s5 * C + lane];
                float v6 = xin[s6 * C + lane];
                float v7 = xin[s7 * C + lane];
                acc += v0; acc += v1; acc += v2; acc += v3;
                acc += v4; acc += v5; acc += v6; acc += v7;
            }
            for (; t < m; t++) {
                int s = __shfl(myidx, t);
                acc += xin[s * C + lane];
            }
        }
        acc *= deg_inv[n];
        xv = xin[(size_t)n * C + lane];
    }
    as_[w][lane] = acc;
    xs[w][lane] = xv;
    __syncthreads();   // weights + own rows visible

    if (n < NN) {
        float o = bs[lane];
        #pragma unroll
        for (int k = 0; k < C; k++) {
            o += as_[w][k] * wl[k * C + lane] + xs[w][k] * wr[k * C + lane];
        }
        o = o >= 0.f ? o : als[lane] * o;
        xout[(size_t)n * C + lane] = o;
    }
}

extern "C" void kernel_launch(void* const* d_in, const int* in_sizes, int n_in,
                              void* d_out, int out_size, void* d_ws, size_t ws_size,
                              hipStream_t stream) {
    const float* x     = (const float*)d_in[0];
    const int*   ei    = (const int*)d_in[1];
    const float* Wl    = (const float*)d_in[2];
    const float* Wr    = (const float*)d_in[3];
    const float* b     = (const float*)d_in[4];
    const float* alpha = (const float*)d_in[5];
    float* out = (float*)d_out;

    const int* src = ei;        // edge_index[0]
    const int* dst = ei + NE;   // edge_index[1]

    // workspace layout
    char* wsp = (char*)d_ws;
    float* deg_inv   = (float*)wsp;                 wsp += (size_t)NN * 4;
    int*   deg_cnt   = (int*)wsp;                   wsp += (size_t)NN * 4;
    int*   row_start = (int*)wsp;                   wsp += (size_t)NN * 4;
    int*   cursor    = (int*)wsp;                   wsp += (size_t)NN * 4;
    int*   bsums     = (int*)wsp;                   wsp += 256 * 4;
    int*   csr_src   = (int*)wsp;                   wsp += (size_t)NE * 4;
    float* x0        = (float*)wsp;                 wsp += (size_t)NN * C * 4;
    float* x1        = (float*)wsp;

    // ---- CSR build ----
    hipMemsetAsync(deg_cnt, 0, NN * sizeof(int), stream);
    hist_kernel<<<1024, 256, 0, stream>>>(dst, deg_cnt);
    scan1_kernel<<<SCAN_NB, 256, 0, stream>>>(deg_cnt, row_start, bsums);
    scan2_kernel<<<1, 256, 0, stream>>>(bsums);
    scan3_kernel<<<(NN + 255) / 256, 256, 0, stream>>>(row_start, bsums, cursor, deg_cnt, deg_inv);
    fill_kernel<<<1024, 256, 0, stream>>>(src, dst, cursor, csr_src);

    // ---- 4 fused layers ----
    const int nblocks = (NN + WPB - 1) / WPB;
    const float* cur = x;
    for (int l = 0; l < NL; l++) {
        float* dest = (l == NL - 1) ? out : ((l & 1) ? x1 : x0);
        fused_layer<<<nblocks, 512, 0, stream>>>(cur, deg_cnt, row_start, csr_src, deg_inv,
                                                 Wl + (size_t)l * C * C,
                                                 Wr + (size_t)l * C * C,
                                                 b + (size_t)l * C,
                                                 alpha + (size_t)l * C,
                                                 dest);
        cur = dest;
    }
}

// Round 4
// 296.505 us; speedup vs baseline: 16.5213x; 1.1991x over previous
//
#include <hip/hip_runtime.h>

#define NN 50000
#define NE 800000
#define C 64
#define NL 4
#define SCAN_NB 196       // ceil(50000/256)

// ---------------- degree histogram (int) ----------------
__global__ void hist_kernel(const int* __restrict__ dst, int* __restrict__ deg_cnt) {
    int i = blockIdx.x * blockDim.x + threadIdx.x;
    int stride = gridDim.x * blockDim.x;
    for (int e = i; e < NE; e += stride)
        atomicAdd(&deg_cnt[dst[e]], 1);
}

// ---------------- 3-kernel exclusive scan over deg_cnt -> row_start ----------------
__global__ __launch_bounds__(256) void scan1_kernel(const int* __restrict__ deg_cnt,
                                                    int* __restrict__ row_start,
                                                    int* __restrict__ bsums) {
    __shared__ int sdata[256];
    int tid = threadIdx.x;
    int i = blockIdx.x * 256 + tid;
    int v = (i < NN) ? deg_cnt[i] : 0;
    sdata[tid] = v;
    __syncthreads();
    for (int off = 1; off < 256; off <<= 1) {
        int t = (tid >= off) ? sdata[tid - off] : 0;
        __syncthreads();
        sdata[tid] += t;
        __syncthreads();
    }
    int incl = sdata[tid];
    if (i < NN) row_start[i] = incl - v;
    if (tid == 255) bsums[blockIdx.x] = incl;
}

__global__ __launch_bounds__(256) void scan2_kernel(int* __restrict__ bsums) {
    __shared__ int sdata[256];
    int tid = threadIdx.x;
    int v = (tid < SCAN_NB) ? bsums[tid] : 0;
    sdata[tid] = v;
    __syncthreads();
    for (int off = 1; off < 256; off <<= 1) {
        int t = (tid >= off) ? sdata[tid - off] : 0;
        __syncthreads();
        sdata[tid] += t;
        __syncthreads();
    }
    if (tid < SCAN_NB) bsums[tid] = sdata[tid] - v;
}

__global__ void scan3_kernel(int* __restrict__ row_start, const int* __restrict__ bsums,
                             int* __restrict__ cursor, const int* __restrict__ deg_cnt,
                             float* __restrict__ deg_inv) {
    int i = blockIdx.x * blockDim.x + threadIdx.x;
    if (i < NN) {
        int rs = row_start[i] + bsums[i >> 8];
        row_start[i] = rs;
        cursor[i] = rs;
        deg_inv[i] = 1.0f / fmaxf((float)deg_cnt[i], 1.0f);
    }
}

// ---------------- CSR fill ----------------
__global__ void fill_kernel(const int* __restrict__ src, const int* __restrict__ dst,
                            int* __restrict__ cursor, int* __restrict__ csr_src) {
    int i = blockIdx.x * blockDim.x + threadIdx.x;
    int stride = gridDim.x * blockDim.x;
    for (int e = i; e < NE; e += stride) {
        int slot = atomicAdd(&cursor[dst[e]], 1);
        csr_src[slot] = src[e];
    }
}

// ---------------- K1: dense transform  y = x@Wl ; z = x@Wr + b ----------------
// 512 threads, 64 nodes/block; thread = (node pair np/np+32, 4 out channels).
__global__ __launch_bounds__(512) void transform_kernel(
    const float* __restrict__ xin,
    const float* __restrict__ Wl, const float* __restrict__ Wr,
    const float* __restrict__ bias,
    float* __restrict__ y, float* __restrict__ z)
{
    __shared__ float wl[C * C];       // [k][c] 16KB
    __shared__ float wr[C * C];       // 16KB
    __shared__ float xs[64][C + 4];   // pad 4 floats: keeps float4 align, kills conflicts

    int tid = threadIdx.x;
    const float4* Wl4 = (const float4*)Wl;
    const float4* Wr4 = (const float4*)Wr;
    for (int i = tid; i < C * C / 4; i += 512) {
        ((float4*)wl)[i] = Wl4[i];
        ((float4*)wr)[i] = Wr4[i];
    }

    int node0 = blockIdx.x * 64;
    for (int i = tid; i < 64 * 16; i += 512) {
        int nl = i >> 4;
        int c4 = i & 15;
        int n = node0 + nl;
        int nc = n < NN ? n : NN - 1;
        float4 v = ((const float4*)xin)[(size_t)nc * 16 + c4];
        *(float4*)&xs[nl][c4 * 4] = v;
    }
    __syncthreads();

    int c4 = tid & 15;
    int np = tid >> 4;                // 0..31
    float4 b4 = ((const float4*)bias)[c4];
    float4 y0 = make_float4(0.f, 0.f, 0.f, 0.f);
    float4 y1 = make_float4(0.f, 0.f, 0.f, 0.f);
    float4 z0 = b4;
    float4 z1 = b4;
    #pragma unroll 16
    for (int k = 0; k < C; k++) {
        float xv0 = xs[np][k];
        float xv1 = xs[np + 32][k];
        float4 wlv = *(const float4*)&wl[k * C + c4 * 4];
        float4 wrv = *(const float4*)&wr[k * C + c4 * 4];
        y0.x += xv0 * wlv.x; y0.y += xv0 * wlv.y; y0.z += xv0 * wlv.z; y0.w += xv0 * wlv.w;
        z0.x += xv0 * wrv.x; z0.y += xv0 * wrv.y; z0.z += xv0 * wrv.z; z0.w += xv0 * wrv.w;
        y1.x += xv1 * wlv.x; y1.y += xv1 * wlv.y; y1.z += xv1 * wlv.z; y1.w += xv1 * wlv.w;
        z1.x += xv1 * wrv.x; z1.y += xv1 * wrv.y; z1.z += xv1 * wrv.z; z1.w += xv1 * wrv.w;
    }
    int n0 = node0 + np;
    int n1 = node0 + np + 32;
    if (n0 < NN) {
        ((float4*)y)[(size_t)n0 * 16 + c4] = y0;
        ((float4*)z)[(size_t)n0 * 16 + c4] = z0;
    }
    if (n1 < NN) {
        ((float4*)y)[(size_t)n1 * 16 + c4] = y1;
        ((float4*)z)[(size_t)n1 * 16 + c4] = z1;
    }
}

// ---------------- K2: gather  out = prelu(deginv * sum y[src] + z) ----------------
// quarter-wave (16 lanes, float4) per node: one wave load = 4 edges x 256B.
__global__ __launch_bounds__(256) void gather_kernel(
    const float4* __restrict__ y4, const float4* __restrict__ z4,
    const int* __restrict__ row_start, const int* __restrict__ deg_cnt,
    const float* __restrict__ deg_inv, const float* __restrict__ alpha,
    const int* __restrict__ csr_src,
    float4* __restrict__ out4)
{
    int tid = threadIdx.x;
    int n = blockIdx.x * 16 + (tid >> 4);   // 3125*16 = 50000 exact
    int ql = tid & 15;

    int rs = row_start[n];
    int d = deg_cnt[n];
    const int* cp = csr_src + rs;

    float4 acc = make_float4(0.f, 0.f, 0.f, 0.f);
    for (int t = 0; t < d; t += 4) {
        int dm1 = d - 1 - t;
        int j1 = dm1 >= 1 ? 1 : 0;
        int j2 = dm1 >= 2 ? 2 : 0;
        int j3 = dm1 >= 3 ? 3 : 0;
        float m1 = dm1 >= 1 ? 1.f : 0.f;
        float m2 = dm1 >= 2 ? 1.f : 0.f;
        float m3 = dm1 >= 3 ? 1.f : 0.f;
        int s0 = cp[t];
        int s1 = cp[t + j1];
        int s2 = cp[t + j2];
        int s3 = cp[t + j3];
        float4 v0 = y4[(size_t)s0 * 16 + ql];
        float4 v1 = y4[(size_t)s1 * 16 + ql];
        float4 v2 = y4[(size_t)s2 * 16 + ql];
        float4 v3 = y4[(size_t)s3 * 16 + ql];
        acc.x += v0.x; acc.y += v0.y; acc.z += v0.z; acc.w += v0.w;
        acc.x += v1.x * m1; acc.y += v1.y * m1; acc.z += v1.z * m1; acc.w += v1.w * m1;
        acc.x += v2.x * m2; acc.y += v2.y * m2; acc.z += v2.z * m2; acc.w += v2.w * m2;
        acc.x += v3.x * m3; acc.y += v3.y * m3; acc.z += v3.z * m3; acc.w += v3.w * m3;
    }

    float di = deg_inv[n];
    float4 zz = z4[(size_t)n * 16 + ql];
    float4 a4 = ((const float4*)alpha)[ql];
    float4 o;
    o.x = di * acc.x + zz.x;
    o.y = di * acc.y + zz.y;
    o.z = di * acc.z + zz.z;
    o.w = di * acc.w + zz.w;
    o.x = o.x >= 0.f ? o.x : a4.x * o.x;
    o.y = o.y >= 0.f ? o.y : a4.y * o.y;
    o.z = o.z >= 0.f ? o.z : a4.z * o.z;
    o.w = o.w >= 0.f ? o.w : a4.w * o.w;
    out4[(size_t)n * 16 + ql] = o;
}

extern "C" void kernel_launch(void* const* d_in, const int* in_sizes, int n_in,
                              void* d_out, int out_size, void* d_ws, size_t ws_size,
                              hipStream_t stream) {
    const float* x     = (const float*)d_in[0];
    const int*   ei    = (const int*)d_in[1];
    const float* Wl    = (const float*)d_in[2];
    const float* Wr    = (const float*)d_in[3];
    const float* b     = (const float*)d_in[4];
    const float* alpha = (const float*)d_in[5];
    float* out = (float*)d_out;

    const int* src = ei;        // edge_index[0]
    const int* dst = ei + NE;   // edge_index[1]

    // workspace layout (~42.5 MB)
    char* wsp = (char*)d_ws;
    float* deg_inv   = (float*)wsp;                 wsp += (size_t)NN * 4;
    int*   deg_cnt   = (int*)wsp;                   wsp += (size_t)NN * 4;
    int*   row_start = (int*)wsp;                   wsp += (size_t)NN * 4;
    int*   cursor    = (int*)wsp;                   wsp += (size_t)NN * 4;
    int*   bsums     = (int*)wsp;                   wsp += 256 * 4;
    int*   csr_src   = (int*)wsp;                   wsp += (size_t)NE * 4;
    float* ybuf      = (float*)wsp;                 wsp += (size_t)NN * C * 4;
    float* zbuf      = (float*)wsp;                 wsp += (size_t)NN * C * 4;
    float* x0        = (float*)wsp;

    // ---- CSR build (once per call) ----
    hipMemsetAsync(deg_cnt, 0, NN * sizeof(int), stream);
    hist_kernel<<<1024, 256, 0, stream>>>(dst, deg_cnt);
    scan1_kernel<<<SCAN_NB, 256, 0, stream>>>(deg_cnt, row_start, bsums);
    scan2_kernel<<<1, 256, 0, stream>>>(bsums);
    scan3_kernel<<<(NN + 255) / 256, 256, 0, stream>>>(row_start, bsums, cursor, deg_cnt, deg_inv);
    fill_kernel<<<1024, 256, 0, stream>>>(src, dst, cursor, csr_src);

    // ---- 4 layers: transform + gather ----
    const float* cur = x;
    for (int l = 0; l < NL; l++) {
        transform_kernel<<<(NN + 63) / 64, 512, 0, stream>>>(
            cur, Wl + (size_t)l * C * C, Wr + (size_t)l * C * C, b + (size_t)l * C,
            ybuf, zbuf);
        float* dest = (l == NL - 1) ? out : x0;
        gather_kernel<<<NN / 16, 256, 0, stream>>>(
            (const float4*)ybuf, (const float4*)zbuf, row_start, deg_cnt,
            deg_inv, alpha + (size_t)l * C, csr_src, (float4*)dest);
        cur = dest;
    }
}

// Round 5
// 290.321 us; speedup vs baseline: 16.8732x; 1.0213x over previous
//
#include <hip/hip_runtime.h>

#define NN 50000
#define NE 800000
#define C 64
#define NL 4
#define SCAN_NB 196       // ceil(50000/256)

// ---------------- degree histogram: 1 edge / thread ----------------
__global__ void hist_kernel(const int* __restrict__ dst, int* __restrict__ deg_cnt) {
    int e = blockIdx.x * blockDim.x + threadIdx.x;
    if (e < NE) atomicAdd(&deg_cnt[dst[e]], 1);
}

// ---------------- scan1: per-block exclusive scan ----------------
__global__ __launch_bounds__(256) void scan1_kernel(const int* __restrict__ deg_cnt,
                                                    int* __restrict__ row_start,
                                                    int* __restrict__ bsums) {
    __shared__ int sdata[256];
    int tid = threadIdx.x;
    int i = blockIdx.x * 256 + tid;
    int v = (i < NN) ? deg_cnt[i] : 0;
    sdata[tid] = v;
    __syncthreads();
    for (int off = 1; off < 256; off <<= 1) {
        int t = (tid >= off) ? sdata[tid - off] : 0;
        __syncthreads();
        sdata[tid] += t;
        __syncthreads();
    }
    int incl = sdata[tid];
    if (i < NN) row_start[i] = incl - v;
    if (tid == 255) bsums[blockIdx.x] = incl;
}

// ---------------- scan23: block-sum scan done redundantly per block + apply ----------------
__global__ __launch_bounds__(256) void scan23_kernel(int* __restrict__ row_start,
                                                     const int* __restrict__ bsums,
                                                     int* __restrict__ cursor,
                                                     const int* __restrict__ deg_cnt,
                                                     float* __restrict__ deg_inv) {
    __shared__ int sdata[256];
    int tid = threadIdx.x;
    int v = (tid < SCAN_NB) ? bsums[tid] : 0;
    sdata[tid] = v;
    __syncthreads();
    for (int off = 1; off < 256; off <<= 1) {
        int t = (tid >= off) ? sdata[tid - off] : 0;
        __syncthreads();
        sdata[tid] += t;
        __syncthreads();
    }
    int b = blockIdx.x;
    int offset = (b == 0) ? 0 : sdata[b - 1];   // exclusive sum of bsums[0..b-1]
    int i = b * 256 + tid;
    if (i < NN) {
        int rs = row_start[i] + offset;
        row_start[i] = rs;
        cursor[i] = rs;
        deg_inv[i] = 1.0f / fmaxf((float)deg_cnt[i], 1.0f);
    }
}

// ---------------- CSR fill: 1 edge / thread ----------------
__global__ void fill_kernel(const int* __restrict__ src, const int* __restrict__ dst,
                            int* __restrict__ cursor, int* __restrict__ csr_src) {
    int e = blockIdx.x * blockDim.x + threadIdx.x;
    if (e < NE) {
        int slot = atomicAdd(&cursor[dst[e]], 1);
        csr_src[slot] = src[e];
    }
}

// ---------------- K1: dense transform  y = x@Wl ; z = x@Wr + b ----------------
__global__ __launch_bounds__(512) void transform_kernel(
    const float* __restrict__ xin,
    const float* __restrict__ Wl, const float* __restrict__ Wr,
    const float* __restrict__ bias,
    float* __restrict__ y, float* __restrict__ z)
{
    __shared__ float wl[C * C];       // [k][c] 16KB
    __shared__ float wr[C * C];       // 16KB
    __shared__ float xs[64][C + 4];

    int tid = threadIdx.x;
    const float4* Wl4 = (const float4*)Wl;
    const float4* Wr4 = (const float4*)Wr;
    for (int i = tid; i < C * C / 4; i += 512) {
        ((float4*)wl)[i] = Wl4[i];
        ((float4*)wr)[i] = Wr4[i];
    }

    int node0 = blockIdx.x * 64;
    for (int i = tid; i < 64 * 16; i += 512) {
        int nl = i >> 4;
        int c4 = i & 15;
        int n = node0 + nl;
        int nc = n < NN ? n : NN - 1;
        float4 v = ((const float4*)xin)[(size_t)nc * 16 + c4];
        *(float4*)&xs[nl][c4 * 4] = v;
    }
    __syncthreads();

    int c4 = tid & 15;
    int np = tid >> 4;                // 0..31
    float4 b4 = ((const float4*)bias)[c4];
    float4 y0 = make_float4(0.f, 0.f, 0.f, 0.f);
    float4 y1 = make_float4(0.f, 0.f, 0.f, 0.f);
    float4 z0 = b4;
    float4 z1 = b4;
    #pragma unroll 16
    for (int k = 0; k < C; k++) {
        float xv0 = xs[np][k];
        float xv1 = xs[np + 32][k];
        float4 wlv = *(const float4*)&wl[k * C + c4 * 4];
        float4 wrv = *(const float4*)&wr[k * C + c4 * 4];
        y0.x += xv0 * wlv.x; y0.y += xv0 * wlv.y; y0.z += xv0 * wlv.z; y0.w += xv0 * wlv.w;
        z0.x += xv0 * wrv.x; z0.y += xv0 * wrv.y; z0.z += xv0 * wrv.z; z0.w += xv0 * wrv.w;
        y1.x += xv1 * wlv.x; y1.y += xv1 * wlv.y; y1.z += xv1 * wlv.z; y1.w += xv1 * wlv.w;
        z1.x += xv1 * wrv.x; z1.y += xv1 * wrv.y; z1.z += xv1 * wrv.z; z1.w += xv1 * wrv.w;
    }
    int n0 = node0 + np;
    int n1 = node0 + np + 32;
    if (n0 < NN) {
        ((float4*)y)[(size_t)n0 * 16 + c4] = y0;
        ((float4*)z)[(size_t)n0 * 16 + c4] = z0;
    }
    if (n1 < NN) {
        ((float4*)y)[(size_t)n1 * 16 + c4] = y1;
        ((float4*)z)[(size_t)n1 * 16 + c4] = z1;
    }
}

// ---------------- K2: gather  out = prelu(deginv * sum y[src] + z) ----------------
// quarter-wave (16 lanes, float4) per node; unroll-8: 8 x 1KB wave-loads in flight.
__global__ __launch_bounds__(256) void gather_kernel(
    const float4* __restrict__ y4, const float4* __restrict__ z4,
    const int* __restrict__ row_start, const int* __restrict__ deg_cnt,
    const float* __restrict__ deg_inv, const float* __restrict__ alpha,
    const int* __restrict__ csr_src,
    float4* __restrict__ out4)
{
    int tid = threadIdx.x;
    int n = blockIdx.x * 16 + (tid >> 4);   // 3125*16 = 50000 exact
    int ql = tid & 15;

    int rs = row_start[n];
    int d = deg_cnt[n];
    const int* cp = csr_src + rs;

    float4 acc = make_float4(0.f, 0.f, 0.f, 0.f);
    for (int t = 0; t < d; t += 8) {
        int lim = d - 1 - t;       // >= 0 inside loop
        int j1 = min(1, lim), j2 = min(2, lim), j3 = min(3, lim);
        int j4 = min(4, lim), j5 = min(5, lim), j6 = min(6, lim), j7 = min(7, lim);
        float m1 = lim >= 1 ? 1.f : 0.f, m2 = lim >= 2 ? 1.f : 0.f;
        float m3 = lim >= 3 ? 1.f : 0.f, m4 = lim >= 4 ? 1.f : 0.f;
        float m5 = lim >= 5 ? 1.f : 0.f, m6 = lim >= 6 ? 1.f : 0.f;
        float m7 = lim >= 7 ? 1.f : 0.f;
        int s0 = cp[t];
        int s1 = cp[t + j1];
        int s2 = cp[t + j2];
        int s3 = cp[t + j3];
        int s4 = cp[t + j4];
        int s5 = cp[t + j5];
        int s6 = cp[t + j6];
        int s7 = cp[t + j7];
        float4 v0 = y4[(size_t)s0 * 16 + ql];
        float4 v1 = y4[(size_t)s1 * 16 + ql];
        float4 v2 = y4[(size_t)s2 * 16 + ql];
        float4 v3 = y4[(size_t)s3 * 16 + ql];
        float4 v4 = y4[(size_t)s4 * 16 + ql];
        float4 v5 = y4[(size_t)s5 * 16 + ql];
        float4 v6 = y4[(size_t)s6 * 16 + ql];
        float4 v7 = y4[(size_t)s7 * 16 + ql];
        acc.x += v0.x;      acc.y += v0.y;      acc.z += v0.z;      acc.w += v0.w;
        acc.x += v1.x * m1; acc.y += v1.y * m1; acc.z += v1.z * m1; acc.w += v1.w * m1;
        acc.x += v2.x * m2; acc.y += v2.y * m2; acc.z += v2.z * m2; acc.w += v2.w * m2;
        acc.x += v3.x * m3; acc.y += v3.y * m3; acc.z += v3.z * m3; acc.w += v3.w * m3;
        acc.x += v4.x * m4; acc.y += v4.y * m4; acc.z += v4.z * m4; acc.w += v4.w * m4;
        acc.x += v5.x * m5; acc.y += v5.y * m5; acc.z += v5.z * m5; acc.w += v5.w * m5;
        acc.x += v6.x * m6; acc.y += v6.y * m6; acc.z += v6.z * m6; acc.w += v6.w * m6;
        acc.x += v7.x * m7; acc.y += v7.y * m7; acc.z += v7.z * m7; acc.w += v7.w * m7;
    }

    float di = deg_inv[n];
    float4 zz = z4[(size_t)n * 16 + ql];
    float4 a4 = ((const float4*)alpha)[ql];
    float4 o;
    o.x = di * acc.x + zz.x;
    o.y = di * acc.y + zz.y;
    o.z = di * acc.z + zz.z;
    o.w = di * acc.w + zz.w;
    o.x = o.x >= 0.f ? o.x : a4.x * o.x;
    o.y = o.y >= 0.f ? o.y : a4.y * o.y;
    o.z = o.z >= 0.f ? o.z : a4.z * o.z;
    o.w = o.w >= 0.f ? o.w : a4.w * o.w;
    out4[(size_t)n * 16 + ql] = o;
}

extern "C" void kernel_launch(void* const* d_in, const int* in_sizes, int n_in,
                              void* d_out, int out_size, void* d_ws, size_t ws_size,
                              hipStream_t stream) {
    const float* x     = (const float*)d_in[0];
    const int*   ei    = (const int*)d_in[1];
    const float* Wl    = (const float*)d_in[2];
    const float* Wr    = (const float*)d_in[3];
    const float* b     = (const float*)d_in[4];
    const float* alpha = (const float*)d_in[5];
    float* out = (float*)d_out;

    const int* src = ei;        // edge_index[0]
    const int* dst = ei + NE;   // edge_index[1]

    // workspace layout
    char* wsp = (char*)d_ws;
    float* deg_inv   = (float*)wsp;                 wsp += (size_t)NN * 4;
    int*   deg_cnt   = (int*)wsp;                   wsp += (size_t)NN * 4;
    int*   row_start = (int*)wsp;                   wsp += (size_t)NN * 4;
    int*   cursor    = (int*)wsp;                   wsp += (size_t)NN * 4;
    int*   bsums     = (int*)wsp;                   wsp += 256 * 4;
    int*   csr_src   = (int*)wsp;                   wsp += (size_t)NE * 4;
    float* ybuf      = (float*)wsp;                 wsp += (size_t)NN * C * 4;
    float* zbuf      = (float*)wsp;                 wsp += (size_t)NN * C * 4;
    float* x0        = (float*)wsp;

    // ---- CSR build (per call) ----
    hipMemsetAsync(deg_cnt, 0, NN * sizeof(int), stream);
    hist_kernel<<<NE / 256, 256, 0, stream>>>(dst, deg_cnt);           // 3125 blocks
    scan1_kernel<<<SCAN_NB, 256, 0, stream>>>(deg_cnt, row_start, bsums);
    scan23_kernel<<<SCAN_NB, 256, 0, stream>>>(row_start, bsums, cursor, deg_cnt, deg_inv);
    fill_kernel<<<NE / 256, 256, 0, stream>>>(src, dst, cursor, csr_src);

    // ---- 4 layers: transform + gather ----
    const float* cur = x;
    for (int l = 0; l < NL; l++) {
        transform_kernel<<<(NN + 63) / 64, 512, 0, stream>>>(
            cur, Wl + (size_t)l * C * C, Wr + (size_t)l * C * C, b + (size_t)l * C,
            ybuf, zbuf);
        float* dest = (l == NL - 1) ? out : x0;
        gather_kernel<<<NN / 16, 256, 0, stream>>>(
            (const float4*)ybuf, (const float4*)zbuf, row_start, deg_cnt,
            deg_inv, alpha + (size_t)l * C, csr_src, (float4*)dest);
        cur = dest;
    }
}

// Round 6
// 284.631 us; speedup vs baseline: 17.2105x; 1.0200x over previous
//
#include <hip/hip_runtime.h>

#define NN 50000
#define NE 800000
#define C 64
#define NL 4
#define SCAN_NB 196       // ceil(50000/256)

// ---------------- degree histogram + per-edge rank (single atomic pass) ----------------
__global__ void hist_rank_kernel(const int* __restrict__ dst, int* __restrict__ deg_cnt,
                                 int* __restrict__ rank) {
    int e = blockIdx.x * blockDim.x + threadIdx.x;
    if (e < NE) rank[e] = atomicAdd(&deg_cnt[dst[e]], 1);
}

// ---------------- scan1: per-block exclusive scan ----------------
__global__ __launch_bounds__(256) void scan1_kernel(const int* __restrict__ deg_cnt,
                                                    int* __restrict__ row_start,
                                                    int* __restrict__ bsums) {
    __shared__ int sdata[256];
    int tid = threadIdx.x;
    int i = blockIdx.x * 256 + tid;
    int v = (i < NN) ? deg_cnt[i] : 0;
    sdata[tid] = v;
    __syncthreads();
    for (int off = 1; off < 256; off <<= 1) {
        int t = (tid >= off) ? sdata[tid - off] : 0;
        __syncthreads();
        sdata[tid] += t;
        __syncthreads();
    }
    int incl = sdata[tid];
    if (i < NN) row_start[i] = incl - v;
    if (tid == 255) bsums[blockIdx.x] = incl;
}

// ---------------- scan23: redundant block-sum scan per block + apply ----------------
__global__ __launch_bounds__(256) void scan23_kernel(int* __restrict__ row_start,
                                                     const int* __restrict__ bsums,
                                                     const int* __restrict__ deg_cnt,
                                                     float* __restrict__ deg_inv) {
    __shared__ int sdata[256];
    int tid = threadIdx.x;
    int v = (tid < SCAN_NB) ? bsums[tid] : 0;
    sdata[tid] = v;
    __syncthreads();
    for (int off = 1; off < 256; off <<= 1) {
        int t = (tid >= off) ? sdata[tid - off] : 0;
        __syncthreads();
        sdata[tid] += t;
        __syncthreads();
    }
    int b = blockIdx.x;
    int offset = (b == 0) ? 0 : sdata[b - 1];
    int i = b * 256 + tid;
    if (i < NN) {
        row_start[i] += offset;
        deg_inv[i] = 1.0f / fmaxf((float)deg_cnt[i], 1.0f);
    }
}

// ---------------- CSR fill: NO atomics ----------------
__global__ void fill_kernel(const int* __restrict__ src, const int* __restrict__ dst,
                            const int* __restrict__ rank, const int* __restrict__ row_start,
                            int* __restrict__ csr_src) {
    int e = blockIdx.x * blockDim.x + threadIdx.x;
    if (e < NE) {
        csr_src[row_start[dst[e]] + rank[e]] = src[e];
    }
}

// ---------------- K1: dense transform  y = x@Wl ; z = x@Wr + b ----------------
__global__ __launch_bounds__(512) void transform_kernel(
    const float* __restrict__ xin,
    const float* __restrict__ Wl, const float* __restrict__ Wr,
    const float* __restrict__ bias,
    float* __restrict__ y, float* __restrict__ z)
{
    __shared__ float wl[C * C];       // [k][c] 16KB
    __shared__ float wr[C * C];       // 16KB
    __shared__ float xs[64][C + 4];

    int tid = threadIdx.x;
    const float4* Wl4 = (const float4*)Wl;
    const float4* Wr4 = (const float4*)Wr;
    for (int i = tid; i < C * C / 4; i += 512) {
        ((float4*)wl)[i] = Wl4[i];
        ((float4*)wr)[i] = Wr4[i];
    }

    int node0 = blockIdx.x * 64;
    for (int i = tid; i < 64 * 16; i += 512) {
        int nl = i >> 4;
        int c4 = i & 15;
        int n = node0 + nl;
        int nc = n < NN ? n : NN - 1;
        float4 v = ((const float4*)xin)[(size_t)nc * 16 + c4];
        *(float4*)&xs[nl][c4 * 4] = v;
    }
    __syncthreads();

    int c4 = tid & 15;
    int np = tid >> 4;                // 0..31
    float4 b4 = ((const float4*)bias)[c4];
    float4 y0 = make_float4(0.f, 0.f, 0.f, 0.f);
    float4 y1 = make_float4(0.f, 0.f, 0.f, 0.f);
    float4 z0 = b4;
    float4 z1 = b4;
    #pragma unroll 16
    for (int k = 0; k < C; k++) {
        float xv0 = xs[np][k];
        float xv1 = xs[np + 32][k];
        float4 wlv = *(const float4*)&wl[k * C + c4 * 4];
        float4 wrv = *(const float4*)&wr[k * C + c4 * 4];
        y0.x += xv0 * wlv.x; y0.y += xv0 * wlv.y; y0.z += xv0 * wlv.z; y0.w += xv0 * wlv.w;
        z0.x += xv0 * wrv.x; z0.y += xv0 * wrv.y; z0.z += xv0 * wrv.z; z0.w += xv0 * wrv.w;
        y1.x += xv1 * wlv.x; y1.y += xv1 * wlv.y; y1.z += xv1 * wlv.z; y1.w += xv1 * wlv.w;
        z1.x += xv1 * wrv.x; z1.y += xv1 * wrv.y; z1.z += xv1 * wrv.z; z1.w += xv1 * wrv.w;
    }
    int n0 = node0 + np;
    int n1 = node0 + np + 32;
    if (n0 < NN) {
        ((float4*)y)[(size_t)n0 * 16 + c4] = y0;
        ((float4*)z)[(size_t)n0 * 16 + c4] = z0;
    }
    if (n1 < NN) {
        ((float4*)y)[(size_t)n1 * 16 + c4] = y1;
        ((float4*)z)[(size_t)n1 * 16 + c4] = z1;
    }
}

// ---------------- K2: gather  out = prelu(deginv * sum y[src] + z) ----------------
// quarter-wave (16 lanes, float4) per node; unroll-8: 8 x 1KB wave-loads in flight.
__global__ __launch_bounds__(256) void gather_kernel(
    const float4* __restrict__ y4, const float4* __restrict__ z4,
    const int* __restrict__ row_start, const int* __restrict__ deg_cnt,
    const float* __restrict__ deg_inv, const float* __restrict__ alpha,
    const int* __restrict__ csr_src,
    float4* __restrict__ out4)
{
    int tid = threadIdx.x;
    int n = blockIdx.x * 16 + (tid >> 4);   // 3125*16 = 50000 exact
    int ql = tid & 15;

    int rs = row_start[n];
    int d = deg_cnt[n];
    const int* cp = csr_src + rs;

    float4 acc = make_float4(0.f, 0.f, 0.f, 0.f);
    for (int t = 0; t < d; t += 8) {
        int lim = d - 1 - t;       // >= 0 inside loop
        int j1 = min(1, lim), j2 = min(2, lim), j3 = min(3, lim);
        int j4 = min(4, lim), j5 = min(5, lim), j6 = min(6, lim), j7 = min(7, lim);
        float m1 = lim >= 1 ? 1.f : 0.f, m2 = lim >= 2 ? 1.f : 0.f;
        float m3 = lim >= 3 ? 1.f : 0.f, m4 = lim >= 4 ? 1.f : 0.f;
        float m5 = lim >= 5 ? 1.f : 0.f, m6 = lim >= 6 ? 1.f : 0.f;
        float m7 = lim >= 7 ? 1.f : 0.f;
        int s0 = cp[t];
        int s1 = cp[t + j1];
        int s2 = cp[t + j2];
        int s3 = cp[t + j3];
        int s4 = cp[t + j4];
        int s5 = cp[t + j5];
        int s6 = cp[t + j6];
        int s7 = cp[t + j7];
        float4 v0 = y4[(size_t)s0 * 16 + ql];
        float4 v1 = y4[(size_t)s1 * 16 + ql];
        float4 v2 = y4[(size_t)s2 * 16 + ql];
        float4 v3 = y4[(size_t)s3 * 16 + ql];
        float4 v4 = y4[(size_t)s4 * 16 + ql];
        float4 v5 = y4[(size_t)s5 * 16 + ql];
        float4 v6 = y4[(size_t)s6 * 16 + ql];
        float4 v7 = y4[(size_t)s7 * 16 + ql];
        acc.x += v0.x;      acc.y += v0.y;      acc.z += v0.z;      acc.w += v0.w;
        acc.x += v1.x * m1; acc.y += v1.y * m1; acc.z += v1.z * m1; acc.w += v1.w * m1;
        acc.x += v2.x * m2; acc.y += v2.y * m2; acc.z += v2.z * m2; acc.w += v2.w * m2;
        acc.x += v3.x * m3; acc.y += v3.y * m3; acc.z += v3.z * m3; acc.w += v3.w * m3;
        acc.x += v4.x * m4; acc.y += v4.y * m4; acc.z += v4.z * m4; acc.w += v4.w * m4;
        acc.x += v5.x * m5; acc.y += v5.y * m5; acc.z += v5.z * m5; acc.w += v5.w * m5;
        acc.x += v6.x * m6; acc.y += v6.y * m6; acc.z += v6.z * m6; acc.w += v6.w * m6;
        acc.x += v7.x * m7; acc.y += v7.y * m7; acc.z += v7.z * m7; acc.w += v7.w * m7;
    }

    float di = deg_inv[n];
    float4 zz = z4[(size_t)n * 16 + ql];
    float4 a4 = ((const float4*)alpha)[ql];
    float4 o;
    o.x = di * acc.x + zz.x;
    o.y = di * acc.y + zz.y;
    o.z = di * acc.z + zz.z;
    o.w = di * acc.w + zz.w;
    o.x = o.x >= 0.f ? o.x : a4.x * o.x;
    o.y = o.y >= 0.f ? o.y : a4.y * o.y;
    o.z = o.z >= 0.f ? o.z : a4.z * o.z;
    o.w = o.w >= 0.f ? o.w : a4.w * o.w;
    out4[(size_t)n * 16 + ql] = o;
}

extern "C" void kernel_launch(void* const* d_in, const int* in_sizes, int n_in,
                              void* d_out, int out_size, void* d_ws, size_t ws_size,
                              hipStream_t stream) {
    const float* x     = (const float*)d_in[0];
    const int*   ei    = (const int*)d_in[1];
    const float* Wl    = (const float*)d_in[2];
    const float* Wr    = (const float*)d_in[3];
    const float* b     = (const float*)d_in[4];
    const float* alpha = (const float*)d_in[5];
    float* out = (float*)d_out;

    const int* src = ei;        // edge_index[0]
    const int* dst = ei + NE;   // edge_index[1]

    // workspace layout
    char* wsp = (char*)d_ws;
    float* deg_inv   = (float*)wsp;                 wsp += (size_t)NN * 4;
    int*   deg_cnt   = (int*)wsp;                   wsp += (size_t)NN * 4;
    int*   row_start = (int*)wsp;                   wsp += (size_t)NN * 4;
    int*   bsums     = (int*)wsp;                   wsp += 256 * 4;
    int*   rankb     = (int*)wsp;                   wsp += (size_t)NE * 4;
    int*   csr_src   = (int*)wsp;                   wsp += (size_t)NE * 4;
    float* ybuf      = (float*)wsp;                 wsp += (size_t)NN * C * 4;
    float* zbuf      = (float*)wsp;                 wsp += (size_t)NN * C * 4;
    float* x0        = (float*)wsp;

    // ---- CSR build (per call) ----
    hipMemsetAsync(deg_cnt, 0, NN * sizeof(int), stream);
    hist_rank_kernel<<<NE / 256, 256, 0, stream>>>(dst, deg_cnt, rankb);
    scan1_kernel<<<SCAN_NB, 256, 0, stream>>>(deg_cnt, row_start, bsums);
    scan23_kernel<<<SCAN_NB, 256, 0, stream>>>(row_start, bsums, deg_cnt, deg_inv);
    fill_kernel<<<NE / 256, 256, 0, stream>>>(src, dst, rankb, row_start, csr_src);

    // ---- 4 layers: transform + gather ----
    const float* cur = x;
    for (int l = 0; l < NL; l++) {
        transform_kernel<<<(NN + 63) / 64, 512, 0, stream>>>(
            cur, Wl + (size_t)l * C * C, Wr + (size_t)l * C * C, b + (size_t)l * C,
            ybuf, zbuf);
        float* dest = (l == NL - 1) ? out : x0;
        gather_kernel<<<NN / 16, 256, 0, stream>>>(
            (const float4*)ybuf, (const float4*)zbuf, row_start, deg_cnt,
            deg_inv, alpha + (size_t)l * C, csr_src, (float4*)dest);
        cur = dest;
    }
}

// Round 7
// 251.533 us; speedup vs baseline: 19.4751x; 1.1316x over previous
//
#include <hip/hip_runtime.h>

#define NN 50000
#define NE 800000
#define C 64
#define NL 4
#define SCAN_NB 196       // ceil(50000/256)

// ---------------- zero deg_cnt (custom: rocclr fillBuffer costs 43us) ----------------
__global__ void zero_kernel(int4* __restrict__ p) {
    int i = blockIdx.x * blockDim.x + threadIdx.x;
    if (i < NN / 4 + 1) p[i] = make_int4(0, 0, 0, 0);   // 50000/4 = 12500
}

// ---------------- degree histogram + per-edge rank (single atomic pass) ----------------
__global__ void hist_rank_kernel(const int* __restrict__ dst, int* __restrict__ deg_cnt,
                                 int* __restrict__ rank) {
    int e = blockIdx.x * blockDim.x + threadIdx.x;
    if (e < NE) rank[e] = atomicAdd(&deg_cnt[dst[e]], 1);
}

// ---------------- scan1: per-block exclusive scan ----------------
__global__ __launch_bounds__(256) void scan1_kernel(const int* __restrict__ deg_cnt,
                                                    int* __restrict__ row_start,
                                                    int* __restrict__ bsums) {
    __shared__ int sdata[256];
    int tid = threadIdx.x;
    int i = blockIdx.x * 256 + tid;
    int v = (i < NN) ? deg_cnt[i] : 0;
    sdata[tid] = v;
    __syncthreads();
    for (int off = 1; off < 256; off <<= 1) {
        int t = (tid >= off) ? sdata[tid - off] : 0;
        __syncthreads();
        sdata[tid] += t;
        __syncthreads();
    }
    int incl = sdata[tid];
    if (i < NN) row_start[i] = incl - v;
    if (tid == 255) bsums[blockIdx.x] = incl;
}

// ---------------- scan23: redundant block-sum scan per block + apply ----------------
__global__ __launch_bounds__(256) void scan23_kernel(int* __restrict__ row_start,
                                                     const int* __restrict__ bsums,
                                                     const int* __restrict__ deg_cnt,
                                                     float* __restrict__ deg_inv) {
    __shared__ int sdata[256];
    int tid = threadIdx.x;
    int v = (tid < SCAN_NB) ? bsums[tid] : 0;
    sdata[tid] = v;
    __syncthreads();
    for (int off = 1; off < 256; off <<= 1) {
        int t = (tid >= off) ? sdata[tid - off] : 0;
        __syncthreads();
        sdata[tid] += t;
        __syncthreads();
    }
    int b = blockIdx.x;
    int offset = (b == 0) ? 0 : sdata[b - 1];
    int i = b * 256 + tid;
    if (i < NN) {
        row_start[i] += offset;
        deg_inv[i] = 1.0f / fmaxf((float)deg_cnt[i], 1.0f);
    }
}

// ---------------- CSR fill: NO atomics ----------------
__global__ void fill_kernel(const int* __restrict__ src, const int* __restrict__ dst,
                            const int* __restrict__ rank, const int* __restrict__ row_start,
                            int* __restrict__ csr_src) {
    int e = blockIdx.x * blockDim.x + threadIdx.x;
    if (e < NE) {
        csr_src[row_start[dst[e]] + rank[e]] = src[e];
    }
}

// ---------------- K1: dense transform  y = x@Wl ; z = x@Wr + b ----------------
__global__ __launch_bounds__(512) void transform_kernel(
    const float* __restrict__ xin,
    const float* __restrict__ Wl, const float* __restrict__ Wr,
    const float* __restrict__ bias,
    float* __restrict__ y, float* __restrict__ z)
{
    __shared__ float wl[C * C];       // [k][c] 16KB
    __shared__ float wr[C * C];       // 16KB
    __shared__ float xs[64][C + 4];

    int tid = threadIdx.x;
    const float4* Wl4 = (const float4*)Wl;
    const float4* Wr4 = (const float4*)Wr;
    for (int i = tid; i < C * C / 4; i += 512) {
        ((float4*)wl)[i] = Wl4[i];
        ((float4*)wr)[i] = Wr4[i];
    }

    int node0 = blockIdx.x * 64;
    for (int i = tid; i < 64 * 16; i += 512) {
        int nl = i >> 4;
        int c4 = i & 15;
        int n = node0 + nl;
        int nc = n < NN ? n : NN - 1;
        float4 v = ((const float4*)xin)[(size_t)nc * 16 + c4];
        *(float4*)&xs[nl][c4 * 4] = v;
    }
    __syncthreads();

    int c4 = tid & 15;
    int np = tid >> 4;                // 0..31
    float4 b4 = ((const float4*)bias)[c4];
    float4 y0 = make_float4(0.f, 0.f, 0.f, 0.f);
    float4 y1 = make_float4(0.f, 0.f, 0.f, 0.f);
    float4 z0 = b4;
    float4 z1 = b4;
    #pragma unroll 16
    for (int k = 0; k < C; k++) {
        float xv0 = xs[np][k];
        float xv1 = xs[np + 32][k];
        float4 wlv = *(const float4*)&wl[k * C + c4 * 4];
        float4 wrv = *(const float4*)&wr[k * C + c4 * 4];
        y0.x += xv0 * wlv.x; y0.y += xv0 * wlv.y; y0.z += xv0 * wlv.z; y0.w += xv0 * wlv.w;
        z0.x += xv0 * wrv.x; z0.y += xv0 * wrv.y; z0.z += xv0 * wrv.z; z0.w += xv0 * wrv.w;
        y1.x += xv1 * wlv.x; y1.y += xv1 * wlv.y; y1.z += xv1 * wlv.z; y1.w += xv1 * wlv.w;
        z1.x += xv1 * wrv.x; z1.y += xv1 * wrv.y; z1.z += xv1 * wrv.z; z1.w += xv1 * wrv.w;
    }
    int n0 = node0 + np;
    int n1 = node0 + np + 32;
    if (n0 < NN) {
        ((float4*)y)[(size_t)n0 * 16 + c4] = y0;
        ((float4*)z)[(size_t)n0 * 16 + c4] = z0;
    }
    if (n1 < NN) {
        ((float4*)y)[(size_t)n1 * 16 + c4] = y1;
        ((float4*)z)[(size_t)n1 * 16 + c4] = z1;
    }
}

// ---------------- K2: gather  out = prelu(deginv * sum y[src] + z) ----------------
// quarter-wave (16 lanes, float4) per node; unroll-8: 8 x 1KB wave-loads in flight.
__global__ __launch_bounds__(256) void gather_kernel(
    const float4* __restrict__ y4, const float4* __restrict__ z4,
    const int* __restrict__ row_start, const int* __restrict__ deg_cnt,
    const float* __restrict__ deg_inv, const float* __restrict__ alpha,
    const int* __restrict__ csr_src,
    float4* __restrict__ out4)
{
    int tid = threadIdx.x;
    int n = blockIdx.x * 16 + (tid >> 4);   // 3125*16 = 50000 exact
    int ql = tid & 15;

    int rs = row_start[n];
    int d = deg_cnt[n];
    const int* cp = csr_src + rs;

    float4 acc = make_float4(0.f, 0.f, 0.f, 0.f);
    for (int t = 0; t < d; t += 8) {
        int lim = d - 1 - t;       // >= 0 inside loop
        int j1 = min(1, lim), j2 = min(2, lim), j3 = min(3, lim);
        int j4 = min(4, lim), j5 = min(5, lim), j6 = min(6, lim), j7 = min(7, lim);
        float m1 = lim >= 1 ? 1.f : 0.f, m2 = lim >= 2 ? 1.f : 0.f;
        float m3 = lim >= 3 ? 1.f : 0.f, m4 = lim >= 4 ? 1.f : 0.f;
        float m5 = lim >= 5 ? 1.f : 0.f, m6 = lim >= 6 ? 1.f : 0.f;
        float m7 = lim >= 7 ? 1.f : 0.f;
        int s0 = cp[t];
        int s1 = cp[t + j1];
        int s2 = cp[t + j2];
        int s3 = cp[t + j3];
        int s4 = cp[t + j4];
        int s5 = cp[t + j5];
        int s6 = cp[t + j6];
        int s7 = cp[t + j7];
        float4 v0 = y4[(size_t)s0 * 16 + ql];
        float4 v1 = y4[(size_t)s1 * 16 + ql];
        float4 v2 = y4[(size_t)s2 * 16 + ql];
        float4 v3 = y4[(size_t)s3 * 16 + ql];
        float4 v4 = y4[(size_t)s4 * 16 + ql];
        float4 v5 = y4[(size_t)s5 * 16 + ql];
        float4 v6 = y4[(size_t)s6 * 16 + ql];
        float4 v7 = y4[(size_t)s7 * 16 + ql];
        acc.x += v0.x;      acc.y += v0.y;      acc.z += v0.z;      acc.w += v0.w;
        acc.x += v1.x * m1; acc.y += v1.y * m1; acc.z += v1.z * m1; acc.w += v1.w * m1;
        acc.x += v2.x * m2; acc.y += v2.y * m2; acc.z += v2.z * m2; acc.w += v2.w * m2;
        acc.x += v3.x * m3; acc.y += v3.y * m3; acc.z += v3.z * m3; acc.w += v3.w * m3;
        acc.x += v4.x * m4; acc.y += v4.y * m4; acc.z += v4.z * m4; acc.w += v4.w * m4;
        acc.x += v5.x * m5; acc.y += v5.y * m5; acc.z += v5.z * m5; acc.w += v5.w * m5;
        acc.x += v6.x * m6; acc.y += v6.y * m6; acc.z += v6.z * m6; acc.w += v6.w * m6;
        acc.x += v7.x * m7; acc.y += v7.y * m7; acc.z += v7.z * m7; acc.w += v7.w * m7;
    }

    float di = deg_inv[n];
    float4 zz = z4[(size_t)n * 16 + ql];
    float4 a4 = ((const float4*)alpha)[ql];
    float4 o;
    o.x = di * acc.x + zz.x;
    o.y = di * acc.y + zz.y;
    o.z = di * acc.z + zz.z;
    o.w = di * acc.w + zz.w;
    o.x = o.x >= 0.f ? o.x : a4.x * o.x;
    o.y = o.y >= 0.f ? o.y : a4.y * o.y;
    o.z = o.z >= 0.f ? o.z : a4.z * o.z;
    o.w = o.w >= 0.f ? o.w : a4.w * o.w;
    out4[(size_t)n * 16 + ql] = o;
}

extern "C" void kernel_launch(void* const* d_in, const int* in_sizes, int n_in,
                              void* d_out, int out_size, void* d_ws, size_t ws_size,
                              hipStream_t stream) {
    const float* x     = (const float*)d_in[0];
    const int*   ei    = (const int*)d_in[1];
    const float* Wl    = (const float*)d_in[2];
    const float* Wr    = (const float*)d_in[3];
    const float* b     = (const float*)d_in[4];
    const float* alpha = (const float*)d_in[5];
    float* out = (float*)d_out;

    const int* src = ei;        // edge_index[0]
    const int* dst = ei + NE;   // edge_index[1]

    // workspace layout (deg_cnt first, 16B-aligned, padded to mult of 4 ints)
    char* wsp = (char*)d_ws;
    int*   deg_cnt   = (int*)wsp;                   wsp += (size_t)(NN + 16) * 4;
    float* deg_inv   = (float*)wsp;                 wsp += (size_t)NN * 4;
    int*   row_start = (int*)wsp;                   wsp += (size_t)NN * 4;
    int*   bsums     = (int*)wsp;                   wsp += 256 * 4;
    int*   rankb     = (int*)wsp;                   wsp += (size_t)NE * 4;
    int*   csr_src   = (int*)wsp;                   wsp += (size_t)NE * 4;
    float* ybuf      = (float*)wsp;                 wsp += (size_t)NN * C * 4;
    float* zbuf      = (float*)wsp;                 wsp += (size_t)NN * C * 4;
    float* x0        = (float*)wsp;

    // ---- CSR build (per call) ----
    zero_kernel<<<(NN / 4 + 256) / 256, 256, 0, stream>>>((int4*)deg_cnt);
    hist_rank_kernel<<<NE / 256, 256, 0, stream>>>(dst, deg_cnt, rankb);
    scan1_kernel<<<SCAN_NB, 256, 0, stream>>>(deg_cnt, row_start, bsums);
    scan23_kernel<<<SCAN_NB, 256, 0, stream>>>(row_start, bsums, deg_cnt, deg_inv);
    fill_kernel<<<NE / 256, 256, 0, stream>>>(src, dst, rankb, row_start, csr_src);

    // ---- 4 layers: transform + gather ----
    const float* cur = x;
    for (int l = 0; l < NL; l++) {
        transform_kernel<<<(NN + 63) / 64, 512, 0, stream>>>(
            cur, Wl + (size_t)l * C * C, Wr + (size_t)l * C * C, b + (size_t)l * C,
            ybuf, zbuf);
        float* dest = (l == NL - 1) ? out : x0;
        gather_kernel<<<NN / 16, 256, 0, stream>>>(
            (const float4*)ybuf, (const float4*)zbuf, row_start, deg_cnt,
            deg_inv, alpha + (size_t)l * C, csr_src, (float4*)dest);
        cur = dest;
    }
}

// Round 8
// 218.272 us; speedup vs baseline: 22.4428x; 1.1524x over previous
//
#include <hip/hip_runtime.h>

#define NN 50000
#define NE 800000
#define C 64
#define NL 4
#define SCAN_NB 196       // ceil(50000/256)

// ---------------- zero deg_cnt ----------------
__global__ void zero_kernel(int4* __restrict__ p) {
    int i = blockIdx.x * blockDim.x + threadIdx.x;
    if (i < NN / 4 + 1) p[i] = make_int4(0, 0, 0, 0);
}

// ---------------- degree histogram + per-edge rank ----------------
__global__ void hist_rank_kernel(const int* __restrict__ dst, int* __restrict__ deg_cnt,
                                 int* __restrict__ rank) {
    int e = blockIdx.x * blockDim.x + threadIdx.x;
    if (e < NE) rank[e] = atomicAdd(&deg_cnt[dst[e]], 1);
}

// ---------------- scan1 ----------------
__global__ __launch_bounds__(256) void scan1_kernel(const int* __restrict__ deg_cnt,
                                                    int* __restrict__ row_start,
                                                    int* __restrict__ bsums) {
    __shared__ int sdata[256];
    int tid = threadIdx.x;
    int i = blockIdx.x * 256 + tid;
    int v = (i < NN) ? deg_cnt[i] : 0;
    sdata[tid] = v;
    __syncthreads();
    for (int off = 1; off < 256; off <<= 1) {
        int t = (tid >= off) ? sdata[tid - off] : 0;
        __syncthreads();
        sdata[tid] += t;
        __syncthreads();
    }
    int incl = sdata[tid];
    if (i < NN) row_start[i] = incl - v;
    if (tid == 255) bsums[blockIdx.x] = incl;
}

// ---------------- scan23 ----------------
__global__ __launch_bounds__(256) void scan23_kernel(int* __restrict__ row_start,
                                                     const int* __restrict__ bsums,
                                                     const int* __restrict__ deg_cnt,
                                                     float* __restrict__ deg_inv) {
    __shared__ int sdata[256];
    int tid = threadIdx.x;
    int v = (tid < SCAN_NB) ? bsums[tid] : 0;
    sdata[tid] = v;
    __syncthreads();
    for (int off = 1; off < 256; off <<= 1) {
        int t = (tid >= off) ? sdata[tid - off] : 0;
        __syncthreads();
        sdata[tid] += t;
        __syncthreads();
    }
    int b = blockIdx.x;
    int offset = (b == 0) ? 0 : sdata[b - 1];
    int i = b * 256 + tid;
    if (i < NN) {
        row_start[i] += offset;
        deg_inv[i] = 1.0f / fmaxf((float)deg_cnt[i], 1.0f);
    }
}

// ---------------- CSR fill (no atomics) ----------------
__global__ void fill_kernel(const int* __restrict__ src, const int* __restrict__ dst,
                            const int* __restrict__ rank, const int* __restrict__ row_start,
                            int* __restrict__ csr_src) {
    int e = blockIdx.x * blockDim.x + threadIdx.x;
    if (e < NE) {
        csr_src[row_start[dst[e]] + rank[e]] = src[e];
    }
}

// ---------------- gather core (16 lanes/node, unroll-8, masked tail) ----------------
__device__ __forceinline__ float4 gather_row(const float4* __restrict__ y4,
                                             const int* __restrict__ cp, int d, int ql) {
    float4 acc = make_float4(0.f, 0.f, 0.f, 0.f);
    for (int t = 0; t < d; t += 8) {
        int lim = d - 1 - t;
        int j1 = min(1, lim), j2 = min(2, lim), j3 = min(3, lim);
        int j4 = min(4, lim), j5 = min(5, lim), j6 = min(6, lim), j7 = min(7, lim);
        float m1 = lim >= 1 ? 1.f : 0.f, m2 = lim >= 2 ? 1.f : 0.f;
        float m3 = lim >= 3 ? 1.f : 0.f, m4 = lim >= 4 ? 1.f : 0.f;
        float m5 = lim >= 5 ? 1.f : 0.f, m6 = lim >= 6 ? 1.f : 0.f;
        float m7 = lim >= 7 ? 1.f : 0.f;
        int s0 = cp[t];
        int s1 = cp[t + j1];
        int s2 = cp[t + j2];
        int s3 = cp[t + j3];
        int s4 = cp[t + j4];
        int s5 = cp[t + j5];
        int s6 = cp[t + j6];
        int s7 = cp[t + j7];
        float4 v0 = y4[(size_t)s0 * 16 + ql];
        float4 v1 = y4[(size_t)s1 * 16 + ql];
        float4 v2 = y4[(size_t)s2 * 16 + ql];
        float4 v3 = y4[(size_t)s3 * 16 + ql];
        float4 v4 = y4[(size_t)s4 * 16 + ql];
        float4 v5 = y4[(size_t)s5 * 16 + ql];
        float4 v6 = y4[(size_t)s6 * 16 + ql];
        float4 v7 = y4[(size_t)s7 * 16 + ql];
        acc.x += v0.x;      acc.y += v0.y;      acc.z += v0.z;      acc.w += v0.w;
        acc.x += v1.x * m1; acc.y += v1.y * m1; acc.z += v1.z * m1; acc.w += v1.w * m1;
        acc.x += v2.x * m2; acc.y += v2.y * m2; acc.z += v2.z * m2; acc.w += v2.w * m2;
        acc.x += v3.x * m3; acc.y += v3.y * m3; acc.z += v3.z * m3; acc.w += v3.w * m3;
        acc.x += v4.x * m4; acc.y += v4.y * m4; acc.z += v4.z * m4; acc.w += v4.w * m4;
        acc.x += v5.x * m5; acc.y += v5.y * m5; acc.z += v5.z * m5; acc.w += v5.w * m5;
        acc.x += v6.x * m6; acc.y += v6.y * m6; acc.z += v6.z * m6; acc.w += v6.w * m6;
        acc.x += v7.x * m7; acc.y += v7.y * m7; acc.z += v7.z * m7; acc.w += v7.w * m7;
    }
    return acc;
}

// ---------------- K1: dense transform (first layer only) ----------------
__global__ __launch_bounds__(512) void transform_kernel(
    const float* __restrict__ xin,
    const float* __restrict__ Wl, const float* __restrict__ Wr,
    const float* __restrict__ bias,
    float* __restrict__ y, float* __restrict__ z)
{
    __shared__ float wl[C * C];
    __shared__ float wr[C * C];
    __shared__ float xs[64][C + 4];

    int tid = threadIdx.x;
    const float4* Wl4 = (const float4*)Wl;
    const float4* Wr4 = (const float4*)Wr;
    for (int i = tid; i < C * C / 4; i += 512) {
        ((float4*)wl)[i] = Wl4[i];
        ((float4*)wr)[i] = Wr4[i];
    }

    int node0 = blockIdx.x * 64;
    for (int i = tid; i < 64 * 16; i += 512) {
        int nl = i >> 4;
        int c4 = i & 15;
        int n = node0 + nl;
        int nc = n < NN ? n : NN - 1;
        float4 v = ((const float4*)xin)[(size_t)nc * 16 + c4];
        *(float4*)&xs[nl][c4 * 4] = v;
    }
    __syncthreads();

    int c4 = tid & 15;
    int np = tid >> 4;
    float4 b4 = ((const float4*)bias)[c4];
    float4 y0 = make_float4(0.f, 0.f, 0.f, 0.f);
    float4 y1 = make_float4(0.f, 0.f, 0.f, 0.f);
    float4 z0 = b4;
    float4 z1 = b4;
    #pragma unroll 16
    for (int k = 0; k < C; k++) {
        float xv0 = xs[np][k];
        float xv1 = xs[np + 32][k];
        float4 wlv = *(const float4*)&wl[k * C + c4 * 4];
        float4 wrv = *(const float4*)&wr[k * C + c4 * 4];
        y0.x += xv0 * wlv.x; y0.y += xv0 * wlv.y; y0.z += xv0 * wlv.z; y0.w += xv0 * wlv.w;
        z0.x += xv0 * wrv.x; z0.y += xv0 * wrv.y; z0.z += xv0 * wrv.z; z0.w += xv0 * wrv.w;
        y1.x += xv1 * wlv.x; y1.y += xv1 * wlv.y; y1.z += xv1 * wlv.z; y1.w += xv1 * wlv.w;
        z1.x += xv1 * wrv.x; z1.y += xv1 * wrv.y; z1.z += xv1 * wrv.z; z1.w += xv1 * wrv.w;
    }
    int n0 = node0 + np;
    int n1 = node0 + np + 32;
    if (n0 < NN) {
        ((float4*)y)[(size_t)n0 * 16 + c4] = y0;
        ((float4*)z)[(size_t)n0 * 16 + c4] = z0;
    }
    if (n1 < NN) {
        ((float4*)y)[(size_t)n1 * 16 + c4] = y1;
        ((float4*)z)[(size_t)n1 * 16 + c4] = z1;
    }
}

// ---------------- fused: gather layer l -> prelu -> LDS -> transform layer l+1 ----------------
// 512 threads = 32 nodes x 16 lanes. x-row never touches global memory.
__global__ __launch_bounds__(512) void fused_gt_kernel(
    const float4* __restrict__ y4, const float4* __restrict__ z4,
    const int* __restrict__ row_start, const int* __restrict__ deg_cnt,
    const float* __restrict__ deg_inv, const float* __restrict__ alpha,
    const int* __restrict__ csr_src,
    const float* __restrict__ Wl2, const float* __restrict__ Wr2,
    const float* __restrict__ bias2,
    float* __restrict__ yout, float* __restrict__ zout)
{
    __shared__ float wl[C * C];
    __shared__ float wr[C * C];
    __shared__ float xs[32][C + 4];
    __shared__ float bs2[C];

    int tid = threadIdx.x;
    // stage next-layer weights (overlaps with gather's global loads)
    for (int i = tid; i < C * C / 4; i += 512) {
        ((float4*)wl)[i] = ((const float4*)Wl2)[i];
        ((float4*)wr)[i] = ((const float4*)Wr2)[i];
    }
    if (tid < C) bs2[tid] = bias2[tid];

    int nl = tid >> 4;        // 0..31
    int ql = tid & 15;
    int n = blockIdx.x * 32 + nl;     // 1563 blocks covers 50016

    float4 o = make_float4(0.f, 0.f, 0.f, 0.f);
    if (n < NN) {
        int rs = row_start[n];
        int d = deg_cnt[n];
        float4 acc = gather_row(y4, csr_src + rs, d, ql);
        float di = deg_inv[n];
        float4 zz = z4[(size_t)n * 16 + ql];
        float4 a4 = ((const float4*)alpha)[ql];
        o.x = di * acc.x + zz.x;
        o.y = di * acc.y + zz.y;
        o.z = di * acc.z + zz.z;
        o.w = di * acc.w + zz.w;
        o.x = o.x >= 0.f ? o.x : a4.x * o.x;
        o.y = o.y >= 0.f ? o.y : a4.y * o.y;
        o.z = o.z >= 0.f ? o.z : a4.z * o.z;
        o.w = o.w >= 0.f ? o.w : a4.w * o.w;
    }
    *(float4*)&xs[nl][ql * 4] = o;
    __syncthreads();

    // transform phase: same thread->node mapping; 4 out channels per thread
    float4 b4 = *(const float4*)&bs2[ql * 4];
    float4 yv = make_float4(0.f, 0.f, 0.f, 0.f);
    float4 zv = b4;
    #pragma unroll 16
    for (int k = 0; k < C; k++) {
        float xv = xs[nl][k];
        float4 wlv = *(const float4*)&wl[k * C + ql * 4];
        float4 wrv = *(const float4*)&wr[k * C + ql * 4];
        yv.x += xv * wlv.x; yv.y += xv * wlv.y; yv.z += xv * wlv.z; yv.w += xv * wlv.w;
        zv.x += xv * wrv.x; zv.y += xv * wrv.y; zv.z += xv * wrv.z; zv.w += xv * wrv.w;
    }
    if (n < NN) {
        ((float4*)yout)[(size_t)n * 16 + ql] = yv;
        ((float4*)zout)[(size_t)n * 16 + ql] = zv;
    }
}

// ---------------- final gather (layer 3): writes d_out ----------------
__global__ __launch_bounds__(256) void gather_kernel(
    const float4* __restrict__ y4, const float4* __restrict__ z4,
    const int* __restrict__ row_start, const int* __restrict__ deg_cnt,
    const float* __restrict__ deg_inv, const float* __restrict__ alpha,
    const int* __restrict__ csr_src,
    float4* __restrict__ out4)
{
    int tid = threadIdx.x;
    int n = blockIdx.x * 16 + (tid >> 4);   // 3125*16 = 50000 exact
    int ql = tid & 15;

    int rs = row_start[n];
    int d = deg_cnt[n];
    float4 acc = gather_row(y4, csr_src + rs, d, ql);

    float di = deg_inv[n];
    float4 zz = z4[(size_t)n * 16 + ql];
    float4 a4 = ((const float4*)alpha)[ql];
    float4 o;
    o.x = di * acc.x + zz.x;
    o.y = di * acc.y + zz.y;
    o.z = di * acc.z + zz.z;
    o.w = di * acc.w + zz.w;
    o.x = o.x >= 0.f ? o.x : a4.x * o.x;
    o.y = o.y >= 0.f ? o.y : a4.y * o.y;
    o.z = o.z >= 0.f ? o.z : a4.z * o.z;
    o.w = o.w >= 0.f ? o.w : a4.w * o.w;
    out4[(size_t)n * 16 + ql] = o;
}

extern "C" void kernel_launch(void* const* d_in, const int* in_sizes, int n_in,
                              void* d_out, int out_size, void* d_ws, size_t ws_size,
                              hipStream_t stream) {
    const float* x     = (const float*)d_in[0];
    const int*   ei    = (const int*)d_in[1];
    const float* Wl    = (const float*)d_in[2];
    const float* Wr    = (const float*)d_in[3];
    const float* b     = (const float*)d_in[4];
    const float* alpha = (const float*)d_in[5];
    float* out = (float*)d_out;

    const int* src = ei;        // edge_index[0]
    const int* dst = ei + NE;   // edge_index[1]

    // workspace layout
    char* wsp = (char*)d_ws;
    int*   deg_cnt   = (int*)wsp;                   wsp += (size_t)(NN + 16) * 4;
    float* deg_inv   = (float*)wsp;                 wsp += (size_t)NN * 4;
    int*   row_start = (int*)wsp;                   wsp += (size_t)NN * 4;
    int*   bsums     = (int*)wsp;                   wsp += 256 * 4;
    int*   rankb     = (int*)wsp;                   wsp += (size_t)NE * 4;
    int*   csr_src   = (int*)wsp;                   wsp += (size_t)NE * 4;
    float* y0buf     = (float*)wsp;                 wsp += (size_t)NN * C * 4;
    float* z0buf     = (float*)wsp;                 wsp += (size_t)NN * C * 4;
    float* y1buf     = (float*)wsp;                 wsp += (size_t)NN * C * 4;
    float* z1buf     = (float*)wsp;

    // ---- CSR build ----
    zero_kernel<<<(NN / 4 + 256) / 256, 256, 0, stream>>>((int4*)deg_cnt);
    hist_rank_kernel<<<NE / 256, 256, 0, stream>>>(dst, deg_cnt, rankb);
    scan1_kernel<<<SCAN_NB, 256, 0, stream>>>(deg_cnt, row_start, bsums);
    scan23_kernel<<<SCAN_NB, 256, 0, stream>>>(row_start, bsums, deg_cnt, deg_inv);
    fill_kernel<<<NE / 256, 256, 0, stream>>>(src, dst, rankb, row_start, csr_src);

    // ---- layer 0 transform ----
    transform_kernel<<<(NN + 63) / 64, 512, 0, stream>>>(
        x, Wl, Wr, b, y0buf, z0buf);

    // ---- fused (gather_l + transform_{l+1}) for l = 0,1,2; ping-pong y/z ----
    const int fblocks = (NN + 31) / 32;   // 1563
    float* ycur = y0buf; float* zcur = z0buf;
    float* ynxt = y1buf; float* znxt = z1buf;
    for (int l = 0; l < NL - 1; l++) {
        fused_gt_kernel<<<fblocks, 512, 0, stream>>>(
            (const float4*)ycur, (const float4*)zcur,
            row_start, deg_cnt, deg_inv, alpha + (size_t)l * C, csr_src,
            Wl + (size_t)(l + 1) * C * C, Wr + (size_t)(l + 1) * C * C,
            b + (size_t)(l + 1) * C,
            ynxt, znxt);
        float* ty = ycur; float* tz = zcur;
        ycur = ynxt; zcur = znxt;
        ynxt = ty;   znxt = tz;
    }

    // ---- final gather (layer 3) -> d_out ----
    gather_kernel<<<NN / 16, 256, 0, stream>>>(
        (const float4*)ycur, (const float4*)zcur, row_start, deg_cnt,
        deg_inv, alpha + (size_t)(NL - 1) * C, csr_src, (float4*)out);
}